// Round 7
// baseline (371.810 us; speedup 1.0000x reference)
//
#include <hip/hip_runtime.h>
#include <cstddef>
#include <cstdint>

#define GAMMA_F 0.99f
#define OMG_F   0.01f      // 1 - gamma
#define EPS_F   1e-5f
#define KN 8192
#define DD 256
#define NN 32768           // B*T

// output layout (float offsets)
#define OFF_ZQ     0
#define OFF_COMMIT 8388608
#define OFF_IDX    8388609
#define OFF_EMB    8421377
#define OFF_MT     10518529
#define OFF_NT     12615681

// segmented-sum chunking
#define C1 32              // positions per level-1 chunk
#define NCH1 (NN / C1)     // 1024 level-1 chunks
#define NREC (NCH1 * 2)    // 2048 level-1 partial records
#define C2 32              // records per level-2 chunk
#define NCH2 (NREC / C2)   // 64 level-2 chunks

typedef _Float16 half8 __attribute__((ext_vector_type(8)));
typedef _Float16 half4 __attribute__((ext_vector_type(4)));
typedef float    f32x4 __attribute__((ext_vector_type(4)));
typedef unsigned long long u64;

// ---------------------------------------------------------------------------
// async 16B global->LDS (DMA: lane i -> lds_base + i*16; base wave-uniform,
// global address must be 16B aligned)
__device__ __forceinline__ void gload16(const void* g, void* l) {
    __builtin_amdgcn_global_load_lds(
        (const __attribute__((address_space(1))) unsigned int*)g,
        (__attribute__((address_space(3))) unsigned int*)l, 16, 0, 0);
}

// sortable pack for exact fp32 rescoring (dist may be negative)
__device__ __forceinline__ u64 packdi(float dist, int n) {
    unsigned u = __float_as_uint(dist);
    u ^= (unsigned)((int)u >> 31) | 0x80000000u;
    return ((u64)u << 32) | (unsigned)n;
}

// ---------------------------------------------------------------------------
// Fused prep: ze -> f16 (all 8192 blocks); W row -> f16 + ||w||^2 (blocks
// 0..2047, one wave per code row); zero the index histogram.
__global__ __launch_bounds__(256) void prep_kernel(
    const float* __restrict__ ze, const float* __restrict__ W,
    _Float16* __restrict__ zh, _Float16* __restrict__ wh,
    float* __restrict__ wsq, unsigned* __restrict__ hist_zero) {
    const int tid = threadIdx.x;
    const size_t gid = (size_t)blockIdx.x * 256 + tid;

    {   // ze conversion, 4 floats per thread
        const size_t i0 = gid * 4;
        const float4 v = *(const float4*)(ze + i0);
        half4 h;
        h[0] = (_Float16)v.x; h[1] = (_Float16)v.y;
        h[2] = (_Float16)v.z; h[3] = (_Float16)v.w;
        *(half4*)(zh + i0) = h;
    }
    if (gid < KN) hist_zero[gid] = 0u;

    if (blockIdx.x < KN / 4) {           // W rows, one wave per row
        const int k = blockIdx.x * 4 + (tid >> 6);
        const int lane = tid & 63;
        const float4 v = *(const float4*)(W + (size_t)k * DD + lane * 4);
        half4 h;
        h[0] = (_Float16)v.x; h[1] = (_Float16)v.y;
        h[2] = (_Float16)v.z; h[3] = (_Float16)v.w;
        *(half4*)(wh + (size_t)k * DD + lane * 4) = h;
        float s = v.x * v.x + v.y * v.y + v.z * v.z + v.w * v.w;
#pragma unroll
        for (int off = 32; off > 0; off >>= 1) s += __shfl_down(s, off, 64);
        if (lane == 0) wsq[k] = s;
    }
}

// ---------------------------------------------------------------------------
// Screening GEMM, f16, K=256. Block = 128 points x 128 codes, 4 waves (2x2).
// (Validated 165us version; tmin2 stored as u32 lo/hi split.)
__global__ __launch_bounds__(256, 4) void screen_kernel(
    const _Float16* __restrict__ zh, const _Float16* __restrict__ wh,
    const float* __restrict__ wsq,
    unsigned* __restrict__ tlo, unsigned* __restrict__ thi) {
    __shared__ __align__(16) _Float16 As[128 * 64];   // points tile, 16 KB
    __shared__ __align__(16) _Float16 Bs[128 * 64];   // codes tile, 16 KB
    __shared__ __align__(16) u64 top2[128][2];        // [point][code-half]

    const int tid  = threadIdx.x;
    const int wave = tid >> 6;
    const int lane = tid & 63;
    const int quad = lane >> 4;
    const int col  = lane & 15;
    const int ph = wave & 1;        // point half of the block tile
    const int ch = wave >> 1;       // code half
    const int pw = ph * 64;
    const int cw = ch * 64;

    const int bm = blockIdx.x >> 6;     // point-block
    const int bn = blockIdx.x & 63;     // code-block
    const int m0 = bm * 128;
    const int n0 = bn * 128;

    f32x4 acc[4][4];                // [ci (codes)][pj (points)]
#pragma unroll
    for (int i = 0; i < 4; i++)
#pragma unroll
        for (int j = 0; j < 4; j++) acc[i][j] = (f32x4){0.f, 0.f, 0.f, 0.f};

    for (int c = 0; c < 4; ++c) {            // K = 256, 4 chunks of 64
        const int d0 = c * 64;
        __syncthreads();
#pragma unroll
        for (int i = 0; i < 4; ++i) {
            const int clin = (wave * 4 + i) * 64 + lane;   // 0..1023
            const int mrow = clin >> 3;
            const int p = clin & 7;
            const int q = p ^ (mrow & 7);                  // swizzled k-chunk
            gload16(zh + (size_t)(m0 + mrow) * DD + d0 + q * 8,
                    As + (wave * 4 + i) * 512);
            gload16(wh + (size_t)(n0 + mrow) * DD + d0 + q * 8,
                    Bs + (wave * 4 + i) * 512);
        }
        __syncthreads();

#pragma unroll
        for (int kk = 0; kk < 2; ++kk) {
            half8 a[4], b[4];
#pragma unroll
            for (int t = 0; t < 4; ++t) {
                const int cr = cw + t * 16 + col;   // code row
                const int pr = pw + t * 16 + col;   // point row
                const int cc = kk * 4 + quad;
                a[t] = *(const half8*)(Bs + cr * 64 + (cc ^ (cr & 7)) * 8);
                b[t] = *(const half8*)(As + pr * 64 + (cc ^ (pr & 7)) * 8);
            }
#pragma unroll
            for (int ci = 0; ci < 4; ++ci)
#pragma unroll
                for (int pj = 0; pj < 4; ++pj)
                    acc[ci][pj] = __builtin_amdgcn_mfma_f32_16x16x32_f16(
                        a[ci], b[pj], acc[ci][pj], 0, 0, 0);
        }
    }

    // wq[ci][v] = wsq[code] + 4096 (offset makes all dists positive -> raw
    // f32 bits monotone as u32)
    float wq[4][4];
#pragma unroll
    for (int ci = 0; ci < 4; ++ci) {
        const float4 t = *(const float4*)(wsq + n0 + cw + ci * 16 + quad * 4);
        wq[ci][0] = t.x + 4096.f; wq[ci][1] = t.y + 4096.f;
        wq[ci][2] = t.z + 4096.f; wq[ci][3] = t.w + 4096.f;
    }
    const unsigned base7 = (unsigned)(cw + quad * 4);

#pragma unroll
    for (int pj = 0; pj < 4; ++pj) {
        unsigned t0 = 0xFFFFFFFFu, t1 = 0xFFFFFFFFu;
#pragma unroll
        for (int ci = 0; ci < 4; ++ci)
#pragma unroll
            for (int v = 0; v < 4; ++v) {
                const float dist = fmaf(-2.0f, acc[ci][pj][v], wq[ci][v]);
                const unsigned x = (__float_as_uint(dist) & ~127u) |
                                   (base7 + ci * 16 + v);
                const unsigned mx = t0 > x ? t0 : x;
                t0 = t0 < x ? t0 : x;
                t1 = t1 < mx ? t1 : mx;
            }
        // merge sorted pairs across the 4 quads (same point col)
#pragma unroll
        for (int mk = 16; mk < 64; mk <<= 1) {
            const unsigned o0 = __shfl_xor(t0, mk, 64);
            const unsigned o1 = __shfl_xor(t1, mk, 64);
            const unsigned lo = t0 < o0 ? t0 : o0;
            const unsigned hi = t0 < o0 ? o0 : t0;
            const unsigned mn = t1 < o1 ? t1 : o1;
            t0 = lo;
            t1 = hi < mn ? hi : mn;
        }
        if (quad == 0)
            top2[pw + pj * 16 + col][ch] = ((u64)t1 << 32) | t0;
    }
    __syncthreads();
    if (tid < 128) {
        const u64 e0 = top2[tid][0], e1 = top2[tid][1];
        const unsigned a0 = (unsigned)e0, a1 = (unsigned)(e0 >> 32);
        const unsigned b0 = (unsigned)e1, b1 = (unsigned)(e1 >> 32);
        const unsigned t0 = a0 < b0 ? a0 : b0;
        const unsigned hi = a0 < b0 ? b0 : a0;
        const unsigned mn = a1 < b1 ? a1 : b1;
        const unsigned t1 = hi < mn ? hi : mn;
        const unsigned c1 = n0 + (t0 & 127u);
        const unsigned c2 = n0 + (t1 & 127u);
        const u64 ent = (u64)(t0 & ~127u) | ((u64)c1 << 32) | ((u64)c2 << 48);
        // transposed layout [tile][point] -> coalesced 512B block writes
        tlo[(size_t)bn * NN + m0 + tid] = (unsigned)ent;
        thi[(size_t)bn * NN + m0 + tid] = (unsigned)(ent >> 32);
    }
}

// ---------------------------------------------------------------------------
// FUSED select = compact + rescore. Per point (one wave): min over 64 tile
// records -> window candidates in LDS; exact fp32 rescore (2-way unrolled:
// independent shuffle chains overlap) -> winning index, zq write, commit
// partial into a tmin2 slot this block alone consumed. NO histogram atomic
// here (moved to hist_kernel -- the hot-code same-line RMW serialization).
__global__ __launch_bounds__(256) void select_kernel(
    const unsigned* __restrict__ tlo, const unsigned* __restrict__ thi,
    const float* __restrict__ ze, const float* __restrict__ W,
    float* __restrict__ idxf, float* __restrict__ zq_out,
    float* __restrict__ partials) {
    __shared__ unsigned sl[4][32];
    __shared__ float wsum[4];
    const int tid = threadIdx.x;
    const int lane = tid & 63;
    const int w = tid >> 6;

    const int n = blockIdx.x * 4 + w;
    const unsigned elo = tlo[(size_t)lane * NN + n];
    const unsigned ehi = thi[(size_t)lane * NN + n];
    const float d1 = __uint_as_float(elo);   // offset +4096, quantized
    float mn = d1;
#pragma unroll
    for (int off = 32; off > 0; off >>= 1)
        mn = fminf(mn, __shfl_xor(mn, off, 64));
    const bool q = d1 <= mn + 1.0f;      // >=25-sigma window incl. quantization
    const u64 bal = __ballot(q);
    if (q) {
        const int rank = __popcll(bal & ((1ull << lane) - 1ull));
        if (rank < 16) {
            sl[w][2 * rank + 0] = ehi & 0xffffu;
            sl[w][2 * rank + 1] = ehi >> 16;
        }
    }
    unsigned m = 2u * (unsigned)__popcll(bal);
    m = m < 32u ? m : 32u;
    __syncthreads();                     // slots visible

    const float4 z = *(const float4*)(ze + (size_t)n * DD + lane * 4);
    u64 best = ~0ull;
    unsigned j = 0;
    for (; j + 2 <= m; j += 2) {         // 2 candidates/iter: chains overlap
        const unsigned c0 = sl[w][j];
        const unsigned c1 = sl[w][j + 1];
        const float4 w0 = *(const float4*)(W + (size_t)c0 * DD + lane * 4);
        const float4 w1 = *(const float4*)(W + (size_t)c1 * DD + lane * 4);
        float d0 = z.x * w0.x + z.y * w0.y + z.z * w0.z + z.w * w0.w;
        float q0 = w0.x * w0.x + w0.y * w0.y + w0.z * w0.z + w0.w * w0.w;
        float d1c = z.x * w1.x + z.y * w1.y + z.z * w1.z + z.w * w1.w;
        float q1 = w1.x * w1.x + w1.y * w1.y + w1.z * w1.z + w1.w * w1.w;
#pragma unroll
        for (int off = 32; off > 0; off >>= 1) {
            d0  += __shfl_xor(d0, off, 64);
            q0  += __shfl_xor(q0, off, 64);
            d1c += __shfl_xor(d1c, off, 64);
            q1  += __shfl_xor(q1, off, 64);
        }
        const u64 p0 = packdi(fmaf(-2.0f, d0, q0), (int)c0);
        const u64 p1 = packdi(fmaf(-2.0f, d1c, q1), (int)c1);
        const u64 pm = p0 < p1 ? p0 : p1;
        best = best < pm ? best : pm;
    }
    if (j < m) {
        const unsigned c0 = sl[w][j];
        const float4 w0 = *(const float4*)(W + (size_t)c0 * DD + lane * 4);
        float d0 = z.x * w0.x + z.y * w0.y + z.z * w0.z + z.w * w0.w;
        float q0 = w0.x * w0.x + w0.y * w0.y + w0.z * w0.z + w0.w * w0.w;
#pragma unroll
        for (int off = 32; off > 0; off >>= 1) {
            d0 += __shfl_xor(d0, off, 64);
            q0 += __shfl_xor(q0, off, 64);
        }
        const u64 p0 = packdi(fmaf(-2.0f, d0, q0), (int)c0);
        best = best < p0 ? best : p0;
    }
    const int idx = (int)(unsigned)(best & 0xFFFFFFFFull);  // wave-uniform
    if (lane == 0) idxf[n] = (float)idx;

    const float4 ww = *(const float4*)(W + (size_t)idx * DD + lane * 4);
    float4 d, o;
    d.x = ww.x - z.x; d.y = ww.y - z.y; d.z = ww.z - z.z; d.w = ww.w - z.w;
    o.x = z.x + d.x; o.y = z.y + d.y; o.z = z.z + d.z; o.w = z.w + d.w;
    *(float4*)(zq_out + (size_t)n * DD + lane * 4) = o;

    float c = d.x * d.x + d.y * d.y + d.z * d.z + d.w * d.w;
#pragma unroll
    for (int off = 32; off > 0; off >>= 1) c += __shfl_down(c, off, 64);

    if (lane == 0) wsum[w] = c;
    __syncthreads();                     // all tmin2 reads of this block done
    if (tid == 0)
        partials[4 * blockIdx.x] = wsum[0] + wsum[1] + wsum[2] + wsum[3];
}

// ---------------------------------------------------------------------------
// Block-aggregated histogram: 128 blocks x 256 points. LDS histogram, then
// one global atomicAdd per TOUCHED bin -> hot code sees <=128 RMWs instead
// of ~12K serialized same-line RMWs (the skew measured in round 1).
__global__ __launch_bounds__(256) void hist_kernel(
    const float* __restrict__ idxf, unsigned* __restrict__ hist) {
    __shared__ unsigned h[KN];
    const int t = threadIdx.x;
    for (int i = t; i < KN; i += 256) h[i] = 0u;
    __syncthreads();
    const int n = blockIdx.x * 256 + t;
    const int idx = (int)idxf[n];
    atomicAdd(&h[idx], 1u);
    __syncthreads();
    for (int i = t; i < KN; i += 256) {
        const unsigned c = h[i];
        if (c) atomicAdd(hist + i, c);
    }
}

// ---------------------------------------------------------------------------
// Single block: exclusive prefix over the 8192-bin histogram -> bucket start
// offsets; nt_new = gamma*Nt + 0.01*hist; commit = sum(partials)/(N*D);
// n = sum(nt_new) -> workspace.
__global__ __launch_bounds__(256) void prefix_kernel(
    const float* __restrict__ Nt_in, float* __restrict__ ntn,
    const float* __restrict__ partials, float* __restrict__ commit_out,
    unsigned* __restrict__ offsets, float* __restrict__ nws) {
    const int t = threadIdx.x;
    unsigned* hist = (unsigned*)ntn;
    const int base = t * 32;
    unsigned loc[32];
    unsigned sum = 0;
#pragma unroll
    for (int i = 0; i < 32; ++i) { loc[i] = hist[base + i]; sum += loc[i]; }

    __shared__ unsigned ssum[256];
    __shared__ float cred[256];
    __shared__ float fred[256];
    ssum[t] = sum;
    float cp = 0.f;
    for (int i = t; i < NN / 4; i += 256) cp += partials[4 * i];
    cred[t] = cp;
    __syncthreads();

    // Hillis-Steele inclusive scan over 256 per-thread totals
    for (int off = 1; off < 256; off <<= 1) {
        const unsigned v = (t >= off) ? ssum[t - off] : 0u;
        __syncthreads();
        ssum[t] += v;
        __syncthreads();
    }
    unsigned run = (t > 0) ? ssum[t - 1] : 0u;   // exclusive base

    // commit tree reduce
    for (int off = 128; off > 0; off >>= 1) {
        if (t < off) cred[t] += cred[t + off];
        __syncthreads();
    }
    if (t == 0) *commit_out = cred[0] * (1.0f / 8388608.0f);

#pragma unroll
    for (int i = 0; i < 32; ++i) {
        offsets[base + i] = run;
        run += loc[i];
    }
    float fs = 0.f;
#pragma unroll
    for (int i = 0; i < 32; ++i) {
        const float v = GAMMA_F * Nt_in[base + i] + OMG_F * (float)loc[i];
        ntn[base + i] = v;
        fs += v;
    }
    fred[t] = fs;
    __syncthreads();
    for (int off = 128; off > 0; off >>= 1) {
        if (t < off) fred[t] += fred[t + off];
        __syncthreads();
    }
    if (t == 0) nws[0] = fred[0];
}

// ---------------------------------------------------------------------------
// Counting-sort scatter with BLOCK-AGGREGATED cursors (blocks 0..127, 256
// points each): LDS count -> one global atomicAdd(offsets+c, count) per
// touched bin reserves a contiguous range -> LDS-rank placement. Hot code:
// <=128 global RMWs (was ~12K). Final offsets state identical (bucket ends).
// All 2048 blocks also do the fused mt pre-init = g*mt_in.
__global__ __launch_bounds__(256) void scatter_kernel(
    const float* __restrict__ idxf, unsigned* __restrict__ offsets,
    unsigned* __restrict__ perm, unsigned* __restrict__ codes,
    const float* __restrict__ mt_in, float* __restrict__ mt_out) {
    __shared__ unsigned h[KN];           // 32 KB
    const int t = threadIdx.x;
    const size_t gid = (size_t)blockIdx.x * 256 + t;
    {   // 2048*256 threads x 4 floats == KN*DD exactly
        const float4 m = *(const float4*)(mt_in + gid * 4);
        float4 r;
        r.x = GAMMA_F * m.x; r.y = GAMMA_F * m.y;
        r.z = GAMMA_F * m.z; r.w = GAMMA_F * m.w;
        *(float4*)(mt_out + gid * 4) = r;
    }
    if (blockIdx.x < NN / 256) {
        for (int i = t; i < KN; i += 256) h[i] = 0u;
        __syncthreads();
        const int idx = (int)idxf[gid];
        const unsigned r = atomicAdd(&h[idx], 1u);   // local rank
        __syncthreads();
        for (int i = t; i < KN; i += 256) {
            const unsigned c = h[i];
            if (c) h[i] = atomicAdd(offsets + i, c); // reserve range -> base
        }
        __syncthreads();
        const unsigned pos = h[idx] + r;
        perm[pos] = (unsigned)gid;
        codes[pos] = (unsigned)idx;
    }
}

// ---------------------------------------------------------------------------
// Segmented sum, level 1: 1024 waves x 32-position chunks over the sorted
// (codes, perm) sequence. Interior runs -> direct write mt_new = g*mt+0.01*s.
// First/last runs of each chunk -> 2 partial records (code-sorted order).
// Worst-case work per wave = 32 rows, independent of bucket skew.
__global__ __launch_bounds__(256) void mt1_kernel(
    const float* __restrict__ ze, const float* __restrict__ mt_in,
    const unsigned* __restrict__ perm, const unsigned* __restrict__ codes,
    float* __restrict__ mt_out, unsigned* __restrict__ prec,
    float* __restrict__ pdata) {
    const int tid = threadIdx.x;
    const int lane = tid & 63;
    const int w = blockIdx.x * 4 + (tid >> 6);   // chunk id, 0..NCH1-1
    const int j0 = w * C1;

    unsigned ccur = codes[j0];
    bool first = true;
    float4 acc = {0.f, 0.f, 0.f, 0.f};

    for (int j = j0; j < j0 + C1; ++j) {
        const unsigned c = codes[j];
        if (c != ccur) {
            if (first) {
                *(float4*)(pdata + (size_t)(2 * w) * DD + lane * 4) = acc;
                if (lane == 0) prec[2 * w] = ccur;
                first = false;
            } else {
                const size_t o = (size_t)ccur * DD + lane * 4;
                const float4 m = *(const float4*)(mt_in + o);
                float4 r;
                r.x = GAMMA_F * m.x + OMG_F * acc.x;
                r.y = GAMMA_F * m.y + OMG_F * acc.y;
                r.z = GAMMA_F * m.z + OMG_F * acc.z;
                r.w = GAMMA_F * m.w + OMG_F * acc.w;
                *(float4*)(mt_out + o) = r;
            }
            acc = (float4){0.f, 0.f, 0.f, 0.f};
            ccur = c;
        }
        const unsigned p = perm[j];
        const float4 z = *(const float4*)(ze + (size_t)p * DD + lane * 4);
        acc.x += z.x; acc.y += z.y; acc.z += z.z; acc.w += z.w;
    }
    // tail: last run always emitted
    if (first) {   // whole chunk was one run -> record + zero dummy (same code)
        *(float4*)(pdata + (size_t)(2 * w) * DD + lane * 4) = acc;
        *(float4*)(pdata + (size_t)(2 * w + 1) * DD + lane * 4) =
            (float4){0.f, 0.f, 0.f, 0.f};
        if (lane == 0) { prec[2 * w] = ccur; prec[2 * w + 1] = ccur; }
    } else {
        *(float4*)(pdata + (size_t)(2 * w + 1) * DD + lane * 4) = acc;
        if (lane == 0) prec[2 * w + 1] = ccur;
    }
}

// ---------------------------------------------------------------------------
// Segmented sum, level 2: 64 waves x 32-record chunks over the 2048 records
// (still code-sorted). Interior runs -> direct write. First/last runs ->
// atomicAdd(0.01*partial) onto mt_out (pre-inited to g*mt in scatter_kernel).
__global__ __launch_bounds__(256) void mt2_kernel(
    const float* __restrict__ mt_in, const unsigned* __restrict__ prec,
    const float* __restrict__ pdata, float* __restrict__ mt_out) {
    const int tid = threadIdx.x;
    const int lane = tid & 63;
    const int w = blockIdx.x * 4 + (tid >> 6);   // 0..NCH2-1
    const int r0 = w * C2;

    unsigned ccur = prec[r0];
    bool first = true;
    float4 acc = {0.f, 0.f, 0.f, 0.f};

    for (int r = r0; r < r0 + C2; ++r) {
        const unsigned c = prec[r];
        if (c != ccur) {
            if (first) {
                float* mp = mt_out + (size_t)ccur * DD + lane * 4;
                atomicAdd(mp + 0, OMG_F * acc.x);
                atomicAdd(mp + 1, OMG_F * acc.y);
                atomicAdd(mp + 2, OMG_F * acc.z);
                atomicAdd(mp + 3, OMG_F * acc.w);
                first = false;
            } else {
                const size_t o = (size_t)ccur * DD + lane * 4;
                const float4 m = *(const float4*)(mt_in + o);
                float4 rr;
                rr.x = GAMMA_F * m.x + OMG_F * acc.x;
                rr.y = GAMMA_F * m.y + OMG_F * acc.y;
                rr.z = GAMMA_F * m.z + OMG_F * acc.z;
                rr.w = GAMMA_F * m.w + OMG_F * acc.w;
                *(float4*)(mt_out + o) = rr;
            }
            acc = (float4){0.f, 0.f, 0.f, 0.f};
            ccur = c;
        }
        const float4 v = *(const float4*)(pdata + (size_t)r * DD + lane * 4);
        acc.x += v.x; acc.y += v.y; acc.z += v.z; acc.w += v.w;
    }
    // last run: always atomic (may continue into the next chunk)
    float* mp = mt_out + (size_t)ccur * DD + lane * 4;
    atomicAdd(mp + 0, OMG_F * acc.x);
    atomicAdd(mp + 1, OMG_F * acc.y);
    atomicAdd(mp + 2, OMG_F * acc.z);
    atomicAdd(mp + 3, OMG_F * acc.w);
}

// ---------------------------------------------------------------------------
// emb = mt_new / Nn; n precomputed by prefix (no per-block 8K reduction).
__global__ __launch_bounds__(256) void final_kernel(
    const float* __restrict__ nt_new, const float* __restrict__ mt_new,
    const float* __restrict__ nws, float* __restrict__ emb_out) {
    const float n = nws[0];
    const size_t i0 = ((size_t)blockIdx.x * 256 + threadIdx.x) * 4;
    const int k = (int)(i0 >> 8);

    const float4 mt = *(const float4*)(mt_new + i0);
    const float Nn = (nt_new[k] + EPS_F) * n / (n + (float)KN * EPS_F);
    float4 e;
    e.x = mt.x / Nn;
    e.y = mt.y / Nn;
    e.z = mt.z / Nn;
    e.w = mt.w / Nn;
    *(float4*)(emb_out + i0) = e;
}

// ---------------------------------------------------------------------------
extern "C" void kernel_launch(void* const* d_in, const int* in_sizes, int n_in,
                              void* d_out, int out_size, void* d_ws, size_t ws_size,
                              hipStream_t stream) {
    const float* ze = (const float*)d_in[0];
    const float* W  = (const float*)d_in[1];
    const float* mt = (const float*)d_in[2];
    const float* Nt = (const float*)d_in[3];

    float* out    = (float*)d_out;
    float* zq_out = out + OFF_ZQ;
    float* commit = out + OFF_COMMIT;
    float* idxf   = out + OFF_IDX;
    float* emb    = out + OFF_EMB;
    float* mtn    = out + OFF_MT;
    float* ntn    = out + OFF_NT;

    // ---- scratch map (all consumed before the real outputs are written) ----
    _Float16* zh = (_Float16*)zq_out;                       // 16.7 MB
    _Float16* wh = (_Float16*)(zq_out + (size_t)NN * DD / 2);   // 4 MB
    float* wsqbuf = zq_out + (size_t)NN * DD / 2 + (size_t)KN * DD / 2;
    unsigned* tlo = (unsigned*)emb;                         // 64*NN u32
    unsigned* thi = tlo + (size_t)64 * NN;                  // 64*NN u32
    float* partials = (float*)tlo;                          // slot b at [4b]
    unsigned* offsets = tlo;                                // [0, 8192)
    unsigned* perm    = tlo + 8192;                         // [8192, 40960)
    unsigned* codes   = tlo + 40960;                        // [40960, 73728)
    unsigned* prec    = tlo + 73728;                        // [73728, 75776)
    float*    pdata   = (float*)tlo + 75779;                // 16B-aligned, 2MB
    unsigned* hist    = (unsigned*)ntn;                     // KN u32
    float*    nws     = (float*)d_ws;                       // 1 float

    // 1) fused prep: ze->f16, W->f16 + ||w||^2, hist zero
    prep_kernel<<<(NN * DD / 4) / 256, 256, 0, stream>>>(
        ze, W, zh, wh, wsqbuf, hist);

    // 2) f16 screening GEMM -> per-(point,tile) top-2 records (lo/hi)
    screen_kernel<<<(NN / 128) * (KN / 128), 256, 0, stream>>>(
        zh, wh, wsqbuf, tlo, thi);

    // 3) fused select: window compaction (LDS) + exact rescore + zq +
    //    commit partial (no histogram atomic)
    select_kernel<<<NN / 4, 256, 0, stream>>>(
        tlo, thi, ze, W, idxf, zq_out, partials);

    // 4) block-aggregated histogram (hot-bin RMWs: ~12K -> <=128)
    hist_kernel<<<NN / 256, 256, 0, stream>>>(idxf, hist);

    // 5) prefix over histogram -> offsets; nt_new; commit; n
    prefix_kernel<<<1, 256, 0, stream>>>(Nt, ntn, partials, commit,
                                         offsets, nws);

    // 6) block-aggregated counting-sort scatter; fused mt pre-init = g*mt
    scatter_kernel<<<(KN * DD / 4) / 256, 256, 0, stream>>>(
        idxf, offsets, perm, codes, mt, mtn);

    // 7) segmented sum level 1: balanced chunks, direct interior writes
    mt1_kernel<<<NCH1 / 4, 256, 0, stream>>>(ze, mt, perm, codes, mtn,
                                             prec, pdata);

    // 8) segmented sum level 2: records, atomic only at chunk boundaries
    mt2_kernel<<<NCH2 / 4, 256, 0, stream>>>(mt, prec, pdata, mtn);

    // 9) emb = mt_new / Nn
    final_kernel<<<(KN * DD / 4) / 256, 256, 0, stream>>>(ntn, mtn, nws, emb);
}

// Round 8
// 340.489 us; speedup vs baseline: 1.0920x; 1.0920x over previous
//
#include <hip/hip_runtime.h>
#include <cstddef>
#include <cstdint>

#define GAMMA_F 0.99f
#define OMG_F   0.01f      // 1 - gamma
#define EPS_F   1e-5f
#define KN 8192
#define DD 256
#define NN 32768           // B*T

// output layout (float offsets)
#define OFF_ZQ     0
#define OFF_COMMIT 8388608
#define OFF_IDX    8388609
#define OFF_EMB    8421377
#define OFF_MT     10518529
#define OFF_NT     12615681

// segmented-sum chunking
#define C1 32              // positions per level-1 chunk
#define NCH1 (NN / C1)     // 1024 level-1 chunks
#define NREC (NCH1 * 2)    // 2048 level-1 partial records
#define C2 32              // records per level-2 chunk
#define NCH2 (NREC / C2)   // 64 level-2 chunks

typedef _Float16 half8 __attribute__((ext_vector_type(8)));
typedef _Float16 half4 __attribute__((ext_vector_type(4)));
typedef float    f32x4 __attribute__((ext_vector_type(4)));
typedef unsigned long long u64;

// ---------------------------------------------------------------------------
// async 16B global->LDS (DMA: lane i -> lds_base + i*16; base wave-uniform,
// global address must be 16B aligned)
__device__ __forceinline__ void gload16(const void* g, void* l) {
    __builtin_amdgcn_global_load_lds(
        (const __attribute__((address_space(1))) unsigned int*)g,
        (__attribute__((address_space(3))) unsigned int*)l, 16, 0, 0);
}

// sortable pack for exact fp32 rescoring (dist may be negative)
__device__ __forceinline__ u64 packdi(float dist, int n) {
    unsigned u = __float_as_uint(dist);
    u ^= (unsigned)((int)u >> 31) | 0x80000000u;
    return ((u64)u << 32) | (unsigned)n;
}

// ---------------------------------------------------------------------------
// Fused prep: ze -> f16 (all 8192 blocks); W row -> f16 + ||w||^2 (blocks
// 0..2047, one wave per code row); zero the index histogram.
__global__ __launch_bounds__(256) void prep_kernel(
    const float* __restrict__ ze, const float* __restrict__ W,
    _Float16* __restrict__ zh, _Float16* __restrict__ wh,
    float* __restrict__ wsq, unsigned* __restrict__ hist_zero) {
    const int tid = threadIdx.x;
    const size_t gid = (size_t)blockIdx.x * 256 + tid;

    {   // ze conversion, 4 floats per thread
        const size_t i0 = gid * 4;
        const float4 v = *(const float4*)(ze + i0);
        half4 h;
        h[0] = (_Float16)v.x; h[1] = (_Float16)v.y;
        h[2] = (_Float16)v.z; h[3] = (_Float16)v.w;
        *(half4*)(zh + i0) = h;
    }
    if (gid < KN) hist_zero[gid] = 0u;

    if (blockIdx.x < KN / 4) {           // W rows, one wave per row
        const int k = blockIdx.x * 4 + (tid >> 6);
        const int lane = tid & 63;
        const float4 v = *(const float4*)(W + (size_t)k * DD + lane * 4);
        half4 h;
        h[0] = (_Float16)v.x; h[1] = (_Float16)v.y;
        h[2] = (_Float16)v.z; h[3] = (_Float16)v.w;
        *(half4*)(wh + (size_t)k * DD + lane * 4) = h;
        float s = v.x * v.x + v.y * v.y + v.z * v.z + v.w * v.w;
#pragma unroll
        for (int off = 32; off > 0; off >>= 1) s += __shfl_down(s, off, 64);
        if (lane == 0) wsq[k] = s;
    }
}

// ---------------------------------------------------------------------------
// Screening GEMM, f16, K=256. Block = 128 points x 128 codes, 4 waves (2x2).
// (Validated 163us version; tmin2 stored as u32 lo/hi split.) FROZEN.
__global__ __launch_bounds__(256, 4) void screen_kernel(
    const _Float16* __restrict__ zh, const _Float16* __restrict__ wh,
    const float* __restrict__ wsq,
    unsigned* __restrict__ tlo, unsigned* __restrict__ thi) {
    __shared__ __align__(16) _Float16 As[128 * 64];   // points tile, 16 KB
    __shared__ __align__(16) _Float16 Bs[128 * 64];   // codes tile, 16 KB
    __shared__ __align__(16) u64 top2[128][2];        // [point][code-half]

    const int tid  = threadIdx.x;
    const int wave = tid >> 6;
    const int lane = tid & 63;
    const int quad = lane >> 4;
    const int col  = lane & 15;
    const int ph = wave & 1;        // point half of the block tile
    const int ch = wave >> 1;       // code half
    const int pw = ph * 64;
    const int cw = ch * 64;

    const int bm = blockIdx.x >> 6;     // point-block
    const int bn = blockIdx.x & 63;     // code-block
    const int m0 = bm * 128;
    const int n0 = bn * 128;

    f32x4 acc[4][4];                // [ci (codes)][pj (points)]
#pragma unroll
    for (int i = 0; i < 4; i++)
#pragma unroll
        for (int j = 0; j < 4; j++) acc[i][j] = (f32x4){0.f, 0.f, 0.f, 0.f};

    for (int c = 0; c < 4; ++c) {            // K = 256, 4 chunks of 64
        const int d0 = c * 64;
        __syncthreads();
#pragma unroll
        for (int i = 0; i < 4; ++i) {
            const int clin = (wave * 4 + i) * 64 + lane;   // 0..1023
            const int mrow = clin >> 3;
            const int p = clin & 7;
            const int q = p ^ (mrow & 7);                  // swizzled k-chunk
            gload16(zh + (size_t)(m0 + mrow) * DD + d0 + q * 8,
                    As + (wave * 4 + i) * 512);
            gload16(wh + (size_t)(n0 + mrow) * DD + d0 + q * 8,
                    Bs + (wave * 4 + i) * 512);
        }
        __syncthreads();

#pragma unroll
        for (int kk = 0; kk < 2; ++kk) {
            half8 a[4], b[4];
#pragma unroll
            for (int t = 0; t < 4; ++t) {
                const int cr = cw + t * 16 + col;   // code row
                const int pr = pw + t * 16 + col;   // point row
                const int cc = kk * 4 + quad;
                a[t] = *(const half8*)(Bs + cr * 64 + (cc ^ (cr & 7)) * 8);
                b[t] = *(const half8*)(As + pr * 64 + (cc ^ (pr & 7)) * 8);
            }
#pragma unroll
            for (int ci = 0; ci < 4; ++ci)
#pragma unroll
                for (int pj = 0; pj < 4; ++pj)
                    acc[ci][pj] = __builtin_amdgcn_mfma_f32_16x16x32_f16(
                        a[ci], b[pj], acc[ci][pj], 0, 0, 0);
        }
    }

    // wq[ci][v] = wsq[code] + 4096 (offset makes all dists positive -> raw
    // f32 bits monotone as u32)
    float wq[4][4];
#pragma unroll
    for (int ci = 0; ci < 4; ++ci) {
        const float4 t = *(const float4*)(wsq + n0 + cw + ci * 16 + quad * 4);
        wq[ci][0] = t.x + 4096.f; wq[ci][1] = t.y + 4096.f;
        wq[ci][2] = t.z + 4096.f; wq[ci][3] = t.w + 4096.f;
    }
    const unsigned base7 = (unsigned)(cw + quad * 4);

#pragma unroll
    for (int pj = 0; pj < 4; ++pj) {
        unsigned t0 = 0xFFFFFFFFu, t1 = 0xFFFFFFFFu;
#pragma unroll
        for (int ci = 0; ci < 4; ++ci)
#pragma unroll
            for (int v = 0; v < 4; ++v) {
                const float dist = fmaf(-2.0f, acc[ci][pj][v], wq[ci][v]);
                const unsigned x = (__float_as_uint(dist) & ~127u) |
                                   (base7 + ci * 16 + v);
                const unsigned mx = t0 > x ? t0 : x;
                t0 = t0 < x ? t0 : x;
                t1 = t1 < mx ? t1 : mx;
            }
        // merge sorted pairs across the 4 quads (same point col)
#pragma unroll
        for (int mk = 16; mk < 64; mk <<= 1) {
            const unsigned o0 = __shfl_xor(t0, mk, 64);
            const unsigned o1 = __shfl_xor(t1, mk, 64);
            const unsigned lo = t0 < o0 ? t0 : o0;
            const unsigned hi = t0 < o0 ? o0 : t0;
            const unsigned mn = t1 < o1 ? t1 : o1;
            t0 = lo;
            t1 = hi < mn ? hi : mn;
        }
        if (quad == 0)
            top2[pw + pj * 16 + col][ch] = ((u64)t1 << 32) | t0;
    }
    __syncthreads();
    if (tid < 128) {
        const u64 e0 = top2[tid][0], e1 = top2[tid][1];
        const unsigned a0 = (unsigned)e0, a1 = (unsigned)(e0 >> 32);
        const unsigned b0 = (unsigned)e1, b1 = (unsigned)(e1 >> 32);
        const unsigned t0 = a0 < b0 ? a0 : b0;
        const unsigned hi = a0 < b0 ? b0 : a0;
        const unsigned mn = a1 < b1 ? a1 : b1;
        const unsigned t1 = hi < mn ? hi : mn;
        const unsigned c1 = n0 + (t0 & 127u);
        const unsigned c2 = n0 + (t1 & 127u);
        const u64 ent = (u64)(t0 & ~127u) | ((u64)c1 << 32) | ((u64)c2 << 48);
        // transposed layout [tile][point] -> coalesced 512B block writes
        tlo[(size_t)bn * NN + m0 + tid] = (unsigned)ent;
        thi[(size_t)bn * NN + m0 + tid] = (unsigned)(ent >> 32);
    }
}

// ---------------------------------------------------------------------------
// FUSED select = compact + rescore. Per point (one wave): min over 64 tile
// records -> window candidates in LDS; exact fp32 rescore (2-way unrolled)
// -> winning index, zq write, histogram bump (scattered u32 atomics are
// cheap -- R7 A/B showed aggregation gains nothing), commit partial into a
// tmin2 slot this block alone consumed.
__global__ __launch_bounds__(256) void select_kernel(
    const unsigned* __restrict__ tlo, const unsigned* __restrict__ thi,
    const float* __restrict__ ze, const float* __restrict__ W,
    float* __restrict__ idxf, float* __restrict__ zq_out,
    unsigned* __restrict__ hist, float* __restrict__ partials) {
    __shared__ unsigned sl[4][32];
    __shared__ float wsum[4];
    const int tid = threadIdx.x;
    const int lane = tid & 63;
    const int w = tid >> 6;

    const int n = blockIdx.x * 4 + w;
    const unsigned elo = tlo[(size_t)lane * NN + n];
    const unsigned ehi = thi[(size_t)lane * NN + n];
    const float d1 = __uint_as_float(elo);   // offset +4096, quantized
    float mn = d1;
#pragma unroll
    for (int off = 32; off > 0; off >>= 1)
        mn = fminf(mn, __shfl_xor(mn, off, 64));
    const bool q = d1 <= mn + 1.0f;      // >=25-sigma window incl. quantization
    const u64 bal = __ballot(q);
    if (q) {
        const int rank = __popcll(bal & ((1ull << lane) - 1ull));
        if (rank < 16) {
            sl[w][2 * rank + 0] = ehi & 0xffffu;
            sl[w][2 * rank + 1] = ehi >> 16;
        }
    }
    unsigned m = 2u * (unsigned)__popcll(bal);
    m = m < 32u ? m : 32u;
    __syncthreads();                     // slots visible

    const float4 z = *(const float4*)(ze + (size_t)n * DD + lane * 4);
    u64 best = ~0ull;
    unsigned j = 0;
    for (; j + 2 <= m; j += 2) {         // 2 candidates/iter: chains overlap
        const unsigned c0 = sl[w][j];
        const unsigned c1 = sl[w][j + 1];
        const float4 w0 = *(const float4*)(W + (size_t)c0 * DD + lane * 4);
        const float4 w1 = *(const float4*)(W + (size_t)c1 * DD + lane * 4);
        float d0 = z.x * w0.x + z.y * w0.y + z.z * w0.z + z.w * w0.w;
        float q0 = w0.x * w0.x + w0.y * w0.y + w0.z * w0.z + w0.w * w0.w;
        float d1c = z.x * w1.x + z.y * w1.y + z.z * w1.z + z.w * w1.w;
        float q1 = w1.x * w1.x + w1.y * w1.y + w1.z * w1.z + w1.w * w1.w;
#pragma unroll
        for (int off = 32; off > 0; off >>= 1) {
            d0  += __shfl_xor(d0, off, 64);
            q0  += __shfl_xor(q0, off, 64);
            d1c += __shfl_xor(d1c, off, 64);
            q1  += __shfl_xor(q1, off, 64);
        }
        const u64 p0 = packdi(fmaf(-2.0f, d0, q0), (int)c0);
        const u64 p1 = packdi(fmaf(-2.0f, d1c, q1), (int)c1);
        const u64 pm = p0 < p1 ? p0 : p1;
        best = best < pm ? best : pm;
    }
    if (j < m) {
        const unsigned c0 = sl[w][j];
        const float4 w0 = *(const float4*)(W + (size_t)c0 * DD + lane * 4);
        float d0 = z.x * w0.x + z.y * w0.y + z.z * w0.z + z.w * w0.w;
        float q0 = w0.x * w0.x + w0.y * w0.y + w0.z * w0.z + w0.w * w0.w;
#pragma unroll
        for (int off = 32; off > 0; off >>= 1) {
            d0 += __shfl_xor(d0, off, 64);
            q0 += __shfl_xor(q0, off, 64);
        }
        const u64 p0 = packdi(fmaf(-2.0f, d0, q0), (int)c0);
        best = best < p0 ? best : p0;
    }
    const int idx = (int)(unsigned)(best & 0xFFFFFFFFull);  // wave-uniform
    if (lane == 0) {
        idxf[n] = (float)idx;
        atomicAdd(hist + idx, 1u);
    }

    const float4 ww = *(const float4*)(W + (size_t)idx * DD + lane * 4);
    float4 d, o;
    d.x = ww.x - z.x; d.y = ww.y - z.y; d.z = ww.z - z.z; d.w = ww.w - z.w;
    o.x = z.x + d.x; o.y = z.y + d.y; o.z = z.z + d.z; o.w = z.w + d.w;
    *(float4*)(zq_out + (size_t)n * DD + lane * 4) = o;

    float c = d.x * d.x + d.y * d.y + d.z * d.z + d.w * d.w;
#pragma unroll
    for (int off = 32; off > 0; off >>= 1) c += __shfl_down(c, off, 64);

    if (lane == 0) wsum[w] = c;
    __syncthreads();                     // all tmin2 reads of this block done
    if (tid == 0)
        partials[4 * blockIdx.x] = wsum[0] + wsum[1] + wsum[2] + wsum[3];
}

// ---------------------------------------------------------------------------
// Single block: exclusive prefix over the 8192-bin histogram -> bucket start
// offsets; nt_new = gamma*Nt + 0.01*hist; commit = sum(partials)/(N*D);
// n = sum(nt_new) -> workspace.
__global__ __launch_bounds__(256) void prefix_kernel(
    const float* __restrict__ Nt_in, float* __restrict__ ntn,
    const float* __restrict__ partials, float* __restrict__ commit_out,
    unsigned* __restrict__ offsets, float* __restrict__ nws) {
    const int t = threadIdx.x;
    unsigned* hist = (unsigned*)ntn;
    const int base = t * 32;
    unsigned loc[32];
    unsigned sum = 0;
#pragma unroll
    for (int i = 0; i < 32; ++i) { loc[i] = hist[base + i]; sum += loc[i]; }

    __shared__ unsigned ssum[256];
    __shared__ float cred[256];
    __shared__ float fred[256];
    ssum[t] = sum;
    float cp = 0.f;
    for (int i = t; i < NN / 4; i += 256) cp += partials[4 * i];
    cred[t] = cp;
    __syncthreads();

    // Hillis-Steele inclusive scan over 256 per-thread totals
    for (int off = 1; off < 256; off <<= 1) {
        const unsigned v = (t >= off) ? ssum[t - off] : 0u;
        __syncthreads();
        ssum[t] += v;
        __syncthreads();
    }
    unsigned run = (t > 0) ? ssum[t - 1] : 0u;   // exclusive base

    // commit tree reduce
    for (int off = 128; off > 0; off >>= 1) {
        if (t < off) cred[t] += cred[t + off];
        __syncthreads();
    }
    if (t == 0) *commit_out = cred[0] * (1.0f / 8388608.0f);

#pragma unroll
    for (int i = 0; i < 32; ++i) {
        offsets[base + i] = run;
        run += loc[i];
    }
    float fs = 0.f;
#pragma unroll
    for (int i = 0; i < 32; ++i) {
        const float v = GAMMA_F * Nt_in[base + i] + OMG_F * (float)loc[i];
        ntn[base + i] = v;
        fs += v;
    }
    fred[t] = fs;
    __syncthreads();
    for (int off = 128; off > 0; off >>= 1) {
        if (t < off) fred[t] += fred[t + off];
        __syncthreads();
    }
    if (t == 0) nws[0] = fred[0];
}

// ---------------------------------------------------------------------------
// Counting-sort scatter (per-point u32 atomics; cheap per R7 A/B) + fused
// ZERO-init of the mt sum buffer s (write-only -- the gamma*mt blend moved
// to final_kernel, saving the pre-init read).
__global__ __launch_bounds__(256) void scatter_kernel(
    const float* __restrict__ idxf, unsigned* __restrict__ offsets,
    unsigned* __restrict__ perm, unsigned* __restrict__ codes,
    float* __restrict__ s_zero) {
    const size_t gid = (size_t)blockIdx.x * 256 + threadIdx.x;
    // 2048*256 threads x 4 floats == KN*DD exactly
    *(float4*)(s_zero + gid * 4) = (float4){0.f, 0.f, 0.f, 0.f};
    if (gid < NN) {
        const int idx = (int)idxf[gid];
        const unsigned pos = atomicAdd(offsets + idx, 1u);
        perm[pos] = (unsigned)gid;
        codes[pos] = (unsigned)idx;
    }
}

// ---------------------------------------------------------------------------
// Segmented sum, level 1: 1024 waves x 32-position chunks over the sorted
// (codes, perm) sequence. Interior runs -> direct write s = 0.01*sum (no
// mt read; blend deferred to final). First/last runs of each chunk -> 2
// partial records (code-sorted order). Worst-case work per wave = 32 rows.
__global__ __launch_bounds__(256) void mt1_kernel(
    const float* __restrict__ ze,
    const unsigned* __restrict__ perm, const unsigned* __restrict__ codes,
    float* __restrict__ s_out, unsigned* __restrict__ prec,
    float* __restrict__ pdata) {
    const int tid = threadIdx.x;
    const int lane = tid & 63;
    const int w = blockIdx.x * 4 + (tid >> 6);   // chunk id, 0..NCH1-1
    const int j0 = w * C1;

    unsigned ccur = codes[j0];
    bool first = true;
    float4 acc = {0.f, 0.f, 0.f, 0.f};

    for (int j = j0; j < j0 + C1; ++j) {
        const unsigned c = codes[j];
        if (c != ccur) {
            if (first) {
                *(float4*)(pdata + (size_t)(2 * w) * DD + lane * 4) = acc;
                if (lane == 0) prec[2 * w] = ccur;
                first = false;
            } else {
                float4 r;
                r.x = OMG_F * acc.x; r.y = OMG_F * acc.y;
                r.z = OMG_F * acc.z; r.w = OMG_F * acc.w;
                *(float4*)(s_out + (size_t)ccur * DD + lane * 4) = r;
            }
            acc = (float4){0.f, 0.f, 0.f, 0.f};
            ccur = c;
        }
        const unsigned p = perm[j];
        const float4 z = *(const float4*)(ze + (size_t)p * DD + lane * 4);
        acc.x += z.x; acc.y += z.y; acc.z += z.z; acc.w += z.w;
    }
    // tail: last run always emitted
    if (first) {   // whole chunk was one run -> record + zero dummy (same code)
        *(float4*)(pdata + (size_t)(2 * w) * DD + lane * 4) = acc;
        *(float4*)(pdata + (size_t)(2 * w + 1) * DD + lane * 4) =
            (float4){0.f, 0.f, 0.f, 0.f};
        if (lane == 0) { prec[2 * w] = ccur; prec[2 * w + 1] = ccur; }
    } else {
        *(float4*)(pdata + (size_t)(2 * w + 1) * DD + lane * 4) = acc;
        if (lane == 0) prec[2 * w + 1] = ccur;
    }
}

// ---------------------------------------------------------------------------
// Segmented sum, level 2: 64 waves x 32-record chunks over the 2048 records
// (still code-sorted). Interior runs -> direct write s = 0.01*sum. First/
// last runs -> atomicAdd(0.01*partial) onto s (zero-inited in scatter).
__global__ __launch_bounds__(256) void mt2_kernel(
    const unsigned* __restrict__ prec,
    const float* __restrict__ pdata, float* __restrict__ s_out) {
    const int tid = threadIdx.x;
    const int lane = tid & 63;
    const int w = blockIdx.x * 4 + (tid >> 6);   // 0..NCH2-1
    const int r0 = w * C2;

    unsigned ccur = prec[r0];
    bool first = true;
    float4 acc = {0.f, 0.f, 0.f, 0.f};

    for (int r = r0; r < r0 + C2; ++r) {
        const unsigned c = prec[r];
        if (c != ccur) {
            if (first) {
                float* mp = s_out + (size_t)ccur * DD + lane * 4;
                atomicAdd(mp + 0, OMG_F * acc.x);
                atomicAdd(mp + 1, OMG_F * acc.y);
                atomicAdd(mp + 2, OMG_F * acc.z);
                atomicAdd(mp + 3, OMG_F * acc.w);
                first = false;
            } else {
                float4 rr;
                rr.x = OMG_F * acc.x; rr.y = OMG_F * acc.y;
                rr.z = OMG_F * acc.z; rr.w = OMG_F * acc.w;
                *(float4*)(s_out + (size_t)ccur * DD + lane * 4) = rr;
            }
            acc = (float4){0.f, 0.f, 0.f, 0.f};
            ccur = c;
        }
        const float4 v = *(const float4*)(pdata + (size_t)r * DD + lane * 4);
        acc.x += v.x; acc.y += v.y; acc.z += v.z; acc.w += v.w;
    }
    // last run: always atomic (may continue into the next chunk)
    float* mp = s_out + (size_t)ccur * DD + lane * 4;
    atomicAdd(mp + 0, OMG_F * acc.x);
    atomicAdd(mp + 1, OMG_F * acc.y);
    atomicAdd(mp + 2, OMG_F * acc.z);
    atomicAdd(mp + 3, OMG_F * acc.w);
}

// ---------------------------------------------------------------------------
// mt_new = gamma*mt + s (in place over the s buffer) and emb = mt_new / Nn.
// n precomputed by prefix.
__global__ __launch_bounds__(256) void final_kernel(
    const float* __restrict__ nt_new, const float* __restrict__ mt_in,
    float* __restrict__ mt_new, const float* __restrict__ nws,
    float* __restrict__ emb_out) {
    const float n = nws[0];
    const size_t i0 = ((size_t)blockIdx.x * 256 + threadIdx.x) * 4;
    const int k = (int)(i0 >> 8);

    const float4 s = *(const float4*)(mt_new + i0);   // holds 0.01*sum
    const float4 m = *(const float4*)(mt_in + i0);
    float4 r;
    r.x = GAMMA_F * m.x + s.x;
    r.y = GAMMA_F * m.y + s.y;
    r.z = GAMMA_F * m.z + s.z;
    r.w = GAMMA_F * m.w + s.w;
    *(float4*)(mt_new + i0) = r;

    const float Nn = (nt_new[k] + EPS_F) * n / (n + (float)KN * EPS_F);
    float4 e;
    e.x = r.x / Nn;
    e.y = r.y / Nn;
    e.z = r.z / Nn;
    e.w = r.w / Nn;
    *(float4*)(emb_out + i0) = e;
}

// ---------------------------------------------------------------------------
extern "C" void kernel_launch(void* const* d_in, const int* in_sizes, int n_in,
                              void* d_out, int out_size, void* d_ws, size_t ws_size,
                              hipStream_t stream) {
    const float* ze = (const float*)d_in[0];
    const float* W  = (const float*)d_in[1];
    const float* mt = (const float*)d_in[2];
    const float* Nt = (const float*)d_in[3];

    float* out    = (float*)d_out;
    float* zq_out = out + OFF_ZQ;
    float* commit = out + OFF_COMMIT;
    float* idxf   = out + OFF_IDX;
    float* emb    = out + OFF_EMB;
    float* mtn    = out + OFF_MT;
    float* ntn    = out + OFF_NT;

    // ---- scratch map (all consumed before the real outputs are written) ----
    _Float16* zh = (_Float16*)zq_out;                       // 16.7 MB
    _Float16* wh = (_Float16*)(zq_out + (size_t)NN * DD / 2);   // 4 MB
    float* wsqbuf = zq_out + (size_t)NN * DD / 2 + (size_t)KN * DD / 2;
    unsigned* tlo = (unsigned*)emb;                         // 64*NN u32
    unsigned* thi = tlo + (size_t)64 * NN;                  // 64*NN u32
    float* partials = (float*)tlo;                          // slot b at [4b]
    unsigned* offsets = tlo;                                // [0, 8192)
    unsigned* perm    = tlo + 8192;                         // [8192, 40960)
    unsigned* codes   = tlo + 40960;                        // [40960, 73728)
    unsigned* prec    = tlo + 73728;                        // [73728, 75776)
    float*    pdata   = (float*)tlo + 75779;                // 16B-aligned, 2MB
    unsigned* hist    = (unsigned*)ntn;                     // KN u32
    float*    nws     = (float*)d_ws;                       // 1 float

    // 1) fused prep: ze->f16, W->f16 + ||w||^2, hist zero
    prep_kernel<<<(NN * DD / 4) / 256, 256, 0, stream>>>(
        ze, W, zh, wh, wsqbuf, hist);

    // 2) f16 screening GEMM -> per-(point,tile) top-2 records (lo/hi)
    screen_kernel<<<(NN / 128) * (KN / 128), 256, 0, stream>>>(
        zh, wh, wsqbuf, tlo, thi);

    // 3) fused select: window compaction (LDS) + exact rescore + zq +
    //    histogram + commit partial (into consumed tmin2 slot)
    select_kernel<<<NN / 4, 256, 0, stream>>>(
        tlo, thi, ze, W, idxf, zq_out, hist, partials);

    // 4) prefix over histogram -> offsets; nt_new; commit; n
    prefix_kernel<<<1, 256, 0, stream>>>(Nt, ntn, partials, commit,
                                         offsets, nws);

    // 5) counting-sort scatter -> perm + codes; fused zero-init of s (mtn)
    scatter_kernel<<<(KN * DD / 4) / 256, 256, 0, stream>>>(
        idxf, offsets, perm, codes, mtn);

    // 6) segmented sum level 1: balanced chunks, direct interior s-writes
    mt1_kernel<<<NCH1 / 4, 256, 0, stream>>>(ze, perm, codes, mtn,
                                             prec, pdata);

    // 7) segmented sum level 2: records; atomics only at chunk boundaries
    mt2_kernel<<<NCH2 / 4, 256, 0, stream>>>(prec, pdata, mtn);

    // 8) mt_new = gamma*mt + s; emb = mt_new / Nn
    final_kernel<<<(KN * DD / 4) / 256, 256, 0, stream>>>(ntn, mt, mtn,
                                                          nws, emb);
}

// Round 9
// 336.780 us; speedup vs baseline: 1.1040x; 1.0110x over previous
//
#include <hip/hip_runtime.h>
#include <cstddef>
#include <cstdint>

#define GAMMA_F 0.99f
#define OMG_F   0.01f      // 1 - gamma
#define EPS_F   1e-5f
#define KN 8192
#define DD 256
#define NN 32768           // B*T

// output layout (float offsets)
#define OFF_ZQ     0
#define OFF_COMMIT 8388608
#define OFF_IDX    8388609
#define OFF_EMB    8421377
#define OFF_MT     10518529
#define OFF_NT     12615681

// segmented-sum chunking (C1=16: 2048 balanced waves, 16 serial iters --
// round-8's C1=32 left mt1 latency-bound at 1024 waves x 32 dependent loads)
#define C1 16              // positions per level-1 chunk
#define NCH1 (NN / C1)     // 2048 level-1 chunks
#define NREC (NCH1 * 2)    // 4096 level-1 partial records
#define C2 16              // records per level-2 chunk
#define NCH2 (NREC / C2)   // 256 level-2 chunks

typedef _Float16 half8 __attribute__((ext_vector_type(8)));
typedef _Float16 half4 __attribute__((ext_vector_type(4)));
typedef float    f32x4 __attribute__((ext_vector_type(4)));
typedef unsigned long long u64;

// ---------------------------------------------------------------------------
// async 16B global->LDS (DMA: lane i -> lds_base + i*16; base wave-uniform,
// global address must be 16B aligned)
__device__ __forceinline__ void gload16(const void* g, void* l) {
    __builtin_amdgcn_global_load_lds(
        (const __attribute__((address_space(1))) unsigned int*)g,
        (__attribute__((address_space(3))) unsigned int*)l, 16, 0, 0);
}

// sortable pack for exact fp32 rescoring (dist may be negative)
__device__ __forceinline__ u64 packdi(float dist, int n) {
    unsigned u = __float_as_uint(dist);
    u ^= (unsigned)((int)u >> 31) | 0x80000000u;
    return ((u64)u << 32) | (unsigned)n;
}

// ---------------------------------------------------------------------------
// Fused prep: ze -> f16 (all 8192 blocks); W row -> f16 + ||w||^2 (blocks
// 0..2047, one wave per code row); zero the index histogram.
__global__ __launch_bounds__(256) void prep_kernel(
    const float* __restrict__ ze, const float* __restrict__ W,
    _Float16* __restrict__ zh, _Float16* __restrict__ wh,
    float* __restrict__ wsq, unsigned* __restrict__ hist_zero) {
    const int tid = threadIdx.x;
    const size_t gid = (size_t)blockIdx.x * 256 + tid;

    {   // ze conversion, 4 floats per thread
        const size_t i0 = gid * 4;
        const float4 v = *(const float4*)(ze + i0);
        half4 h;
        h[0] = (_Float16)v.x; h[1] = (_Float16)v.y;
        h[2] = (_Float16)v.z; h[3] = (_Float16)v.w;
        *(half4*)(zh + i0) = h;
    }
    if (gid < KN) hist_zero[gid] = 0u;

    if (blockIdx.x < KN / 4) {           // W rows, one wave per row
        const int k = blockIdx.x * 4 + (tid >> 6);
        const int lane = tid & 63;
        const float4 v = *(const float4*)(W + (size_t)k * DD + lane * 4);
        half4 h;
        h[0] = (_Float16)v.x; h[1] = (_Float16)v.y;
        h[2] = (_Float16)v.z; h[3] = (_Float16)v.w;
        *(half4*)(wh + (size_t)k * DD + lane * 4) = h;
        float s = v.x * v.x + v.y * v.y + v.z * v.z + v.w * v.w;
#pragma unroll
        for (int off = 32; off > 0; off >>= 1) s += __shfl_down(s, off, 64);
        if (lane == 0) wsq[k] = s;
    }
}

// ---------------------------------------------------------------------------
// Screening GEMM, f16, K=256. Block = 128 points x 128 codes, 4 waves (2x2).
// (Validated 161us version; tmin2 stored as u32 lo/hi split.) FROZEN.
__global__ __launch_bounds__(256, 4) void screen_kernel(
    const _Float16* __restrict__ zh, const _Float16* __restrict__ wh,
    const float* __restrict__ wsq,
    unsigned* __restrict__ tlo, unsigned* __restrict__ thi) {
    __shared__ __align__(16) _Float16 As[128 * 64];   // points tile, 16 KB
    __shared__ __align__(16) _Float16 Bs[128 * 64];   // codes tile, 16 KB
    __shared__ __align__(16) u64 top2[128][2];        // [point][code-half]

    const int tid  = threadIdx.x;
    const int wave = tid >> 6;
    const int lane = tid & 63;
    const int quad = lane >> 4;
    const int col  = lane & 15;
    const int ph = wave & 1;        // point half of the block tile
    const int ch = wave >> 1;       // code half
    const int pw = ph * 64;
    const int cw = ch * 64;

    const int bm = blockIdx.x >> 6;     // point-block
    const int bn = blockIdx.x & 63;     // code-block
    const int m0 = bm * 128;
    const int n0 = bn * 128;

    f32x4 acc[4][4];                // [ci (codes)][pj (points)]
#pragma unroll
    for (int i = 0; i < 4; i++)
#pragma unroll
        for (int j = 0; j < 4; j++) acc[i][j] = (f32x4){0.f, 0.f, 0.f, 0.f};

    for (int c = 0; c < 4; ++c) {            // K = 256, 4 chunks of 64
        const int d0 = c * 64;
        __syncthreads();
#pragma unroll
        for (int i = 0; i < 4; ++i) {
            const int clin = (wave * 4 + i) * 64 + lane;   // 0..1023
            const int mrow = clin >> 3;
            const int p = clin & 7;
            const int q = p ^ (mrow & 7);                  // swizzled k-chunk
            gload16(zh + (size_t)(m0 + mrow) * DD + d0 + q * 8,
                    As + (wave * 4 + i) * 512);
            gload16(wh + (size_t)(n0 + mrow) * DD + d0 + q * 8,
                    Bs + (wave * 4 + i) * 512);
        }
        __syncthreads();

#pragma unroll
        for (int kk = 0; kk < 2; ++kk) {
            half8 a[4], b[4];
#pragma unroll
            for (int t = 0; t < 4; ++t) {
                const int cr = cw + t * 16 + col;   // code row
                const int pr = pw + t * 16 + col;   // point row
                const int cc = kk * 4 + quad;
                a[t] = *(const half8*)(Bs + cr * 64 + (cc ^ (cr & 7)) * 8);
                b[t] = *(const half8*)(As + pr * 64 + (cc ^ (pr & 7)) * 8);
            }
#pragma unroll
            for (int ci = 0; ci < 4; ++ci)
#pragma unroll
                for (int pj = 0; pj < 4; ++pj)
                    acc[ci][pj] = __builtin_amdgcn_mfma_f32_16x16x32_f16(
                        a[ci], b[pj], acc[ci][pj], 0, 0, 0);
        }
    }

    // wq[ci][v] = wsq[code] + 4096 (offset makes all dists positive -> raw
    // f32 bits monotone as u32)
    float wq[4][4];
#pragma unroll
    for (int ci = 0; ci < 4; ++ci) {
        const float4 t = *(const float4*)(wsq + n0 + cw + ci * 16 + quad * 4);
        wq[ci][0] = t.x + 4096.f; wq[ci][1] = t.y + 4096.f;
        wq[ci][2] = t.z + 4096.f; wq[ci][3] = t.w + 4096.f;
    }
    const unsigned base7 = (unsigned)(cw + quad * 4);

#pragma unroll
    for (int pj = 0; pj < 4; ++pj) {
        unsigned t0 = 0xFFFFFFFFu, t1 = 0xFFFFFFFFu;
#pragma unroll
        for (int ci = 0; ci < 4; ++ci)
#pragma unroll
            for (int v = 0; v < 4; ++v) {
                const float dist = fmaf(-2.0f, acc[ci][pj][v], wq[ci][v]);
                const unsigned x = (__float_as_uint(dist) & ~127u) |
                                   (base7 + ci * 16 + v);
                const unsigned mx = t0 > x ? t0 : x;
                t0 = t0 < x ? t0 : x;
                t1 = t1 < mx ? t1 : mx;
            }
        // merge sorted pairs across the 4 quads (same point col)
#pragma unroll
        for (int mk = 16; mk < 64; mk <<= 1) {
            const unsigned o0 = __shfl_xor(t0, mk, 64);
            const unsigned o1 = __shfl_xor(t1, mk, 64);
            const unsigned lo = t0 < o0 ? t0 : o0;
            const unsigned hi = t0 < o0 ? o0 : t0;
            const unsigned mn = t1 < o1 ? t1 : o1;
            t0 = lo;
            t1 = hi < mn ? hi : mn;
        }
        if (quad == 0)
            top2[pw + pj * 16 + col][ch] = ((u64)t1 << 32) | t0;
    }
    __syncthreads();
    if (tid < 128) {
        const u64 e0 = top2[tid][0], e1 = top2[tid][1];
        const unsigned a0 = (unsigned)e0, a1 = (unsigned)(e0 >> 32);
        const unsigned b0 = (unsigned)e1, b1 = (unsigned)(e1 >> 32);
        const unsigned t0 = a0 < b0 ? a0 : b0;
        const unsigned hi = a0 < b0 ? b0 : a0;
        const unsigned mn = a1 < b1 ? a1 : b1;
        const unsigned t1 = hi < mn ? hi : mn;
        const unsigned c1 = n0 + (t0 & 127u);
        const unsigned c2 = n0 + (t1 & 127u);
        const u64 ent = (u64)(t0 & ~127u) | ((u64)c1 << 32) | ((u64)c2 << 48);
        // transposed layout [tile][point] -> coalesced 512B block writes
        tlo[(size_t)bn * NN + m0 + tid] = (unsigned)ent;
        thi[(size_t)bn * NN + m0 + tid] = (unsigned)(ent >> 32);
    }
}

// ---------------------------------------------------------------------------
// FUSED select = compact + rescore. Per point (one wave): min over 64 tile
// records -> window candidates in LDS; exact fp32 rescore (2-way unrolled)
// -> winning index, zq write, histogram bump, commit partial (contiguous
// slot in d_ws -> coalesced prefix read).
__global__ __launch_bounds__(256) void select_kernel(
    const unsigned* __restrict__ tlo, const unsigned* __restrict__ thi,
    const float* __restrict__ ze, const float* __restrict__ W,
    float* __restrict__ idxf, float* __restrict__ zq_out,
    unsigned* __restrict__ hist, float* __restrict__ partials) {
    __shared__ unsigned sl[4][32];
    __shared__ float wsum[4];
    const int tid = threadIdx.x;
    const int lane = tid & 63;
    const int w = tid >> 6;

    const int n = blockIdx.x * 4 + w;
    const unsigned elo = tlo[(size_t)lane * NN + n];
    const unsigned ehi = thi[(size_t)lane * NN + n];
    const float d1 = __uint_as_float(elo);   // offset +4096, quantized
    float mn = d1;
#pragma unroll
    for (int off = 32; off > 0; off >>= 1)
        mn = fminf(mn, __shfl_xor(mn, off, 64));
    const bool q = d1 <= mn + 1.0f;      // >=25-sigma window incl. quantization
    const u64 bal = __ballot(q);
    if (q) {
        const int rank = __popcll(bal & ((1ull << lane) - 1ull));
        if (rank < 16) {
            sl[w][2 * rank + 0] = ehi & 0xffffu;
            sl[w][2 * rank + 1] = ehi >> 16;
        }
    }
    unsigned m = 2u * (unsigned)__popcll(bal);
    m = m < 32u ? m : 32u;
    __syncthreads();                     // slots visible

    const float4 z = *(const float4*)(ze + (size_t)n * DD + lane * 4);
    u64 best = ~0ull;
    unsigned j = 0;
    for (; j + 2 <= m; j += 2) {         // 2 candidates/iter: chains overlap
        const unsigned c0 = sl[w][j];
        const unsigned c1 = sl[w][j + 1];
        const float4 w0 = *(const float4*)(W + (size_t)c0 * DD + lane * 4);
        const float4 w1 = *(const float4*)(W + (size_t)c1 * DD + lane * 4);
        float d0 = z.x * w0.x + z.y * w0.y + z.z * w0.z + z.w * w0.w;
        float q0 = w0.x * w0.x + w0.y * w0.y + w0.z * w0.z + w0.w * w0.w;
        float d1c = z.x * w1.x + z.y * w1.y + z.z * w1.z + z.w * w1.w;
        float q1 = w1.x * w1.x + w1.y * w1.y + w1.z * w1.z + w1.w * w1.w;
#pragma unroll
        for (int off = 32; off > 0; off >>= 1) {
            d0  += __shfl_xor(d0, off, 64);
            q0  += __shfl_xor(q0, off, 64);
            d1c += __shfl_xor(d1c, off, 64);
            q1  += __shfl_xor(q1, off, 64);
        }
        const u64 p0 = packdi(fmaf(-2.0f, d0, q0), (int)c0);
        const u64 p1 = packdi(fmaf(-2.0f, d1c, q1), (int)c1);
        const u64 pm = p0 < p1 ? p0 : p1;
        best = best < pm ? best : pm;
    }
    if (j < m) {
        const unsigned c0 = sl[w][j];
        const float4 w0 = *(const float4*)(W + (size_t)c0 * DD + lane * 4);
        float d0 = z.x * w0.x + z.y * w0.y + z.z * w0.z + z.w * w0.w;
        float q0 = w0.x * w0.x + w0.y * w0.y + w0.z * w0.z + w0.w * w0.w;
#pragma unroll
        for (int off = 32; off > 0; off >>= 1) {
            d0 += __shfl_xor(d0, off, 64);
            q0 += __shfl_xor(q0, off, 64);
        }
        const u64 p0 = packdi(fmaf(-2.0f, d0, q0), (int)c0);
        best = best < p0 ? best : p0;
    }
    const int idx = (int)(unsigned)(best & 0xFFFFFFFFull);  // wave-uniform
    if (lane == 0) {
        idxf[n] = (float)idx;
        atomicAdd(hist + idx, 1u);
    }

    const float4 ww = *(const float4*)(W + (size_t)idx * DD + lane * 4);
    float4 d, o;
    d.x = ww.x - z.x; d.y = ww.y - z.y; d.z = ww.z - z.z; d.w = ww.w - z.w;
    o.x = z.x + d.x; o.y = z.y + d.y; o.z = z.z + d.z; o.w = z.w + d.w;
    *(float4*)(zq_out + (size_t)n * DD + lane * 4) = o;

    float c = d.x * d.x + d.y * d.y + d.z * d.z + d.w * d.w;
#pragma unroll
    for (int off = 32; off > 0; off >>= 1) c += __shfl_down(c, off, 64);

    if (lane == 0) wsum[w] = c;
    __syncthreads();
    if (tid == 0)
        partials[blockIdx.x] = wsum[0] + wsum[1] + wsum[2] + wsum[3];
}

// ---------------------------------------------------------------------------
// Single block: exclusive prefix over the 8192-bin histogram -> bucket start
// offsets; nt_new = gamma*Nt + 0.01*hist; commit = sum(partials)/(N*D);
// n = sum(nt_new) -> workspace.
__global__ __launch_bounds__(256) void prefix_kernel(
    const float* __restrict__ Nt_in, float* __restrict__ ntn,
    const float* __restrict__ partials, float* __restrict__ commit_out,
    unsigned* __restrict__ offsets, float* __restrict__ nws) {
    const int t = threadIdx.x;
    unsigned* hist = (unsigned*)ntn;
    const int base = t * 32;
    unsigned loc[32];
    unsigned sum = 0;
#pragma unroll
    for (int i = 0; i < 32; ++i) { loc[i] = hist[base + i]; sum += loc[i]; }

    __shared__ unsigned ssum[256];
    __shared__ float cred[256];
    __shared__ float fred[256];
    ssum[t] = sum;
    float cp = 0.f;
    for (int i = t; i < NN / 4; i += 256) cp += partials[i];   // coalesced
    cred[t] = cp;
    __syncthreads();

    // Hillis-Steele inclusive scan over 256 per-thread totals
    for (int off = 1; off < 256; off <<= 1) {
        const unsigned v = (t >= off) ? ssum[t - off] : 0u;
        __syncthreads();
        ssum[t] += v;
        __syncthreads();
    }
    unsigned run = (t > 0) ? ssum[t - 1] : 0u;   // exclusive base

    // commit tree reduce
    for (int off = 128; off > 0; off >>= 1) {
        if (t < off) cred[t] += cred[t + off];
        __syncthreads();
    }
    if (t == 0) *commit_out = cred[0] * (1.0f / 8388608.0f);

#pragma unroll
    for (int i = 0; i < 32; ++i) {
        offsets[base + i] = run;
        run += loc[i];
    }
    float fs = 0.f;
#pragma unroll
    for (int i = 0; i < 32; ++i) {
        const float v = GAMMA_F * Nt_in[base + i] + OMG_F * (float)loc[i];
        ntn[base + i] = v;
        fs += v;
    }
    fred[t] = fs;
    __syncthreads();
    for (int off = 128; off > 0; off >>= 1) {
        if (t < off) fred[t] += fred[t + off];
        __syncthreads();
    }
    if (t == 0) nws[0] = fred[0];
}

// ---------------------------------------------------------------------------
// Counting-sort scatter (per-point u32 atomics; cheap per R7 A/B) + fused
// ZERO-init of the mt sum buffer s (write-only).
__global__ __launch_bounds__(256) void scatter_kernel(
    const float* __restrict__ idxf, unsigned* __restrict__ offsets,
    unsigned* __restrict__ perm, unsigned* __restrict__ codes,
    float* __restrict__ s_zero) {
    const size_t gid = (size_t)blockIdx.x * 256 + threadIdx.x;
    // 2048*256 threads x 4 floats == KN*DD exactly
    *(float4*)(s_zero + gid * 4) = (float4){0.f, 0.f, 0.f, 0.f};
    if (gid < NN) {
        const int idx = (int)idxf[gid];
        const unsigned pos = atomicAdd(offsets + idx, 1u);
        perm[pos] = (unsigned)gid;
        codes[pos] = (unsigned)idx;
    }
}

// ---------------------------------------------------------------------------
// Segmented sum, level 1: 2048 waves x 16-position chunks over the sorted
// (codes, perm) sequence. Interior runs -> direct write s = 0.01*sum.
// First/last runs of each chunk -> 2 partial records (code-sorted order).
// Worst-case work per wave = 16 rows, independent of bucket skew.
__global__ __launch_bounds__(256) void mt1_kernel(
    const float* __restrict__ ze,
    const unsigned* __restrict__ perm, const unsigned* __restrict__ codes,
    float* __restrict__ s_out, unsigned* __restrict__ prec,
    float* __restrict__ pdata) {
    const int tid = threadIdx.x;
    const int lane = tid & 63;
    const int w = blockIdx.x * 4 + (tid >> 6);   // chunk id, 0..NCH1-1
    const int j0 = w * C1;

    unsigned ccur = codes[j0];
    bool first = true;
    float4 acc = {0.f, 0.f, 0.f, 0.f};

    for (int j = j0; j < j0 + C1; ++j) {
        const unsigned c = codes[j];
        if (c != ccur) {
            if (first) {
                *(float4*)(pdata + (size_t)(2 * w) * DD + lane * 4) = acc;
                if (lane == 0) prec[2 * w] = ccur;
                first = false;
            } else {
                float4 r;
                r.x = OMG_F * acc.x; r.y = OMG_F * acc.y;
                r.z = OMG_F * acc.z; r.w = OMG_F * acc.w;
                *(float4*)(s_out + (size_t)ccur * DD + lane * 4) = r;
            }
            acc = (float4){0.f, 0.f, 0.f, 0.f};
            ccur = c;
        }
        const unsigned p = perm[j];
        const float4 z = *(const float4*)(ze + (size_t)p * DD + lane * 4);
        acc.x += z.x; acc.y += z.y; acc.z += z.z; acc.w += z.w;
    }
    // tail: last run always emitted
    if (first) {   // whole chunk was one run -> record + zero dummy (same code)
        *(float4*)(pdata + (size_t)(2 * w) * DD + lane * 4) = acc;
        *(float4*)(pdata + (size_t)(2 * w + 1) * DD + lane * 4) =
            (float4){0.f, 0.f, 0.f, 0.f};
        if (lane == 0) { prec[2 * w] = ccur; prec[2 * w + 1] = ccur; }
    } else {
        *(float4*)(pdata + (size_t)(2 * w + 1) * DD + lane * 4) = acc;
        if (lane == 0) prec[2 * w + 1] = ccur;
    }
}

// ---------------------------------------------------------------------------
// Segmented sum, level 2: 256 waves x 16-record chunks over the 4096 records
// (still code-sorted). Interior runs -> direct write s = 0.01*sum. First/
// last runs -> atomicAdd(0.01*partial) onto s (zero-inited in scatter).
__global__ __launch_bounds__(256) void mt2_kernel(
    const unsigned* __restrict__ prec,
    const float* __restrict__ pdata, float* __restrict__ s_out) {
    const int tid = threadIdx.x;
    const int lane = tid & 63;
    const int w = blockIdx.x * 4 + (tid >> 6);   // 0..NCH2-1
    const int r0 = w * C2;

    unsigned ccur = prec[r0];
    bool first = true;
    float4 acc = {0.f, 0.f, 0.f, 0.f};

    for (int r = r0; r < r0 + C2; ++r) {
        const unsigned c = prec[r];
        if (c != ccur) {
            if (first) {
                float* mp = s_out + (size_t)ccur * DD + lane * 4;
                atomicAdd(mp + 0, OMG_F * acc.x);
                atomicAdd(mp + 1, OMG_F * acc.y);
                atomicAdd(mp + 2, OMG_F * acc.z);
                atomicAdd(mp + 3, OMG_F * acc.w);
                first = false;
            } else {
                float4 rr;
                rr.x = OMG_F * acc.x; rr.y = OMG_F * acc.y;
                rr.z = OMG_F * acc.z; rr.w = OMG_F * acc.w;
                *(float4*)(s_out + (size_t)ccur * DD + lane * 4) = rr;
            }
            acc = (float4){0.f, 0.f, 0.f, 0.f};
            ccur = c;
        }
        const float4 v = *(const float4*)(pdata + (size_t)r * DD + lane * 4);
        acc.x += v.x; acc.y += v.y; acc.z += v.z; acc.w += v.w;
    }
    // last run: always atomic (may continue into the next chunk)
    float* mp = s_out + (size_t)ccur * DD + lane * 4;
    atomicAdd(mp + 0, OMG_F * acc.x);
    atomicAdd(mp + 1, OMG_F * acc.y);
    atomicAdd(mp + 2, OMG_F * acc.z);
    atomicAdd(mp + 3, OMG_F * acc.w);
}

// ---------------------------------------------------------------------------
// mt_new = gamma*mt + s (in place over the s buffer) and emb = mt_new / Nn.
// n precomputed by prefix.
__global__ __launch_bounds__(256) void final_kernel(
    const float* __restrict__ nt_new, const float* __restrict__ mt_in,
    float* __restrict__ mt_new, const float* __restrict__ nws,
    float* __restrict__ emb_out) {
    const float n = nws[0];
    const size_t i0 = ((size_t)blockIdx.x * 256 + threadIdx.x) * 4;
    const int k = (int)(i0 >> 8);

    const float4 s = *(const float4*)(mt_new + i0);   // holds 0.01*sum
    const float4 m = *(const float4*)(mt_in + i0);
    float4 r;
    r.x = GAMMA_F * m.x + s.x;
    r.y = GAMMA_F * m.y + s.y;
    r.z = GAMMA_F * m.z + s.z;
    r.w = GAMMA_F * m.w + s.w;
    *(float4*)(mt_new + i0) = r;

    const float Nn = (nt_new[k] + EPS_F) * n / (n + (float)KN * EPS_F);
    float4 e;
    e.x = r.x / Nn;
    e.y = r.y / Nn;
    e.z = r.z / Nn;
    e.w = r.w / Nn;
    *(float4*)(emb_out + i0) = e;
}

// ---------------------------------------------------------------------------
extern "C" void kernel_launch(void* const* d_in, const int* in_sizes, int n_in,
                              void* d_out, int out_size, void* d_ws, size_t ws_size,
                              hipStream_t stream) {
    const float* ze = (const float*)d_in[0];
    const float* W  = (const float*)d_in[1];
    const float* mt = (const float*)d_in[2];
    const float* Nt = (const float*)d_in[3];

    float* out    = (float*)d_out;
    float* zq_out = out + OFF_ZQ;
    float* commit = out + OFF_COMMIT;
    float* idxf   = out + OFF_IDX;
    float* emb    = out + OFF_EMB;
    float* mtn    = out + OFF_MT;
    float* ntn    = out + OFF_NT;

    // ---- scratch map (all consumed before the real outputs are written) ----
    // zq region:  zh | wh | wsq -> consumed by screen; select overwrites zq.
    // emb+mt:     tmin2 u32 lo/hi split (4,194,304 u32 exactly). After
    //             select: offsets/perm/codes/prec/pdata in the emb half
    //             (pdata [77827, 1126403) < 2097152 -> never touches mtn/s).
    // nt region:  hist (KN u32) -> nt_new in place.
    // d_ws:       nws (1 float) + contiguous commit partials (NN/4 floats).
    _Float16* zh = (_Float16*)zq_out;                       // 16.7 MB
    _Float16* wh = (_Float16*)(zq_out + (size_t)NN * DD / 2);   // 4 MB
    float* wsqbuf = zq_out + (size_t)NN * DD / 2 + (size_t)KN * DD / 2;
    unsigned* tlo = (unsigned*)emb;                         // 64*NN u32
    unsigned* thi = tlo + (size_t)64 * NN;                  // 64*NN u32
    unsigned* offsets = tlo;                                // [0, 8192)
    unsigned* perm    = tlo + 8192;                         // [8192, 40960)
    unsigned* codes   = tlo + 40960;                        // [40960, 73728)
    unsigned* prec    = tlo + 73728;                        // [73728, 77824)
    float*    pdata   = (float*)tlo + 77827;                // 16B-aligned,
                                                            // NREC*DD = 4.2MB
    unsigned* hist    = (unsigned*)ntn;                     // KN u32
    float*    nws      = (float*)d_ws;                      // 1 float
    float*    partials = (float*)d_ws + 4;                  // NN/4 floats

    // 1) fused prep: ze->f16, W->f16 + ||w||^2, hist zero
    prep_kernel<<<(NN * DD / 4) / 256, 256, 0, stream>>>(
        ze, W, zh, wh, wsqbuf, hist);

    // 2) f16 screening GEMM -> per-(point,tile) top-2 records (lo/hi)
    screen_kernel<<<(NN / 128) * (KN / 128), 256, 0, stream>>>(
        zh, wh, wsqbuf, tlo, thi);

    // 3) fused select: window compaction (LDS) + exact rescore + zq +
    //    histogram + commit partial (contiguous, in d_ws)
    select_kernel<<<NN / 4, 256, 0, stream>>>(
        tlo, thi, ze, W, idxf, zq_out, hist, partials);

    // 4) prefix over histogram -> offsets; nt_new; commit; n
    prefix_kernel<<<1, 256, 0, stream>>>(Nt, ntn, partials, commit,
                                         offsets, nws);

    // 5) counting-sort scatter -> perm + codes; fused zero-init of s (mtn)
    scatter_kernel<<<(KN * DD / 4) / 256, 256, 0, stream>>>(
        idxf, offsets, perm, codes, mtn);

    // 6) segmented sum level 1: 2048 balanced chunks (2x parallelism vs R8)
    mt1_kernel<<<NCH1 / 4, 256, 0, stream>>>(ze, perm, codes, mtn,
                                             prec, pdata);

    // 7) segmented sum level 2: 256 chunks (4x vs R8)
    mt2_kernel<<<NCH2 / 4, 256, 0, stream>>>(prec, pdata, mtn);

    // 8) mt_new = gamma*mt + s; emb = mt_new / Nn
    final_kernel<<<(KN * DD / 4) / 256, 256, 0, stream>>>(ntn, mt, mtn,
                                                          nws, emb);
}